// Round 19
// baseline (772.452 us; speedup 1.0000x reference)
//
#include <hip/hip_runtime.h>
#include <math.h>

#define BATCH   8
#define NTOK    10150
#define DIMC    768
#define INNERC  300
#define HEADS   6
#define DHEAD   50
#define NQ      100
#define NBH     48          // BATCH*HEADS
#define NSPLIT  32
#define CHUNK   320         // 32*320 = 10240 >= 10150
#define SCALE   0.14142135623730951f   // 50^-0.5
#define MTOT    (BATCH*NTOK)           // 81200
#define XDK     320                    // padded K stride for xd planes
#define NEGBIG  -1.0e30f

typedef __attribute__((ext_vector_type(8))) short short8;
typedef __attribute__((ext_vector_type(4))) float f32x4;

__device__ __forceinline__ ushort f2bf(float x) {
  uint u = __float_as_uint(x);
  uint r = (u + 0x7fffu + ((u >> 16) & 1u)) >> 16;
  return (ushort)r;
}
__device__ __forceinline__ float bf2f(ushort h) {
  return __uint_as_float(((uint)h) << 16);
}
// async global->LDS DMA, 16B per lane; LDS dest = wave-uniform base + lane*16
__device__ __forceinline__ void gload_lds16(const void* g, void* l) {
  __builtin_amdgcn_global_load_lds(
      (const __attribute__((address_space(1))) unsigned int*)g,
      (__attribute__((address_space(3))) unsigned int*)l, 16, 0, 0);
}

// ---------------------------------------------------------------------------
// Pre-split fp32 -> padded hi/lo bf16 planes.  dst is [Rp][Cp]; src [R][C].
// ---------------------------------------------------------------------------
__global__ void split_pad(const float* __restrict__ src, ushort* __restrict__ dHi,
                          ushort* __restrict__ dLo, int R, int C, int Rp, int Cp) {
  const int total = Rp * Cp;
  for (int i = blockIdx.x * blockDim.x + threadIdx.x; i < total;
       i += gridDim.x * blockDim.x) {
    const int r = i / Cp, c = i % Cp;
    const float v = (r < R && c < C) ? src[r * C + c] : 0.f;
    const ushort hh = f2bf(v);
    dHi[i] = hh;
    dLo[i] = f2bf(v - bf2f(hh));
  }
}

// Zero the k-pad columns (300..319) of the xd planes.
// MUST run AFTER attn1_combine (delta aliases xdHi) and BEFORE bcast/gemm2.
__global__ void zero_xd_pad(ushort* __restrict__ xdHi, ushort* __restrict__ xdLo) {
  const int total = MTOT * 20;
  for (int i = blockIdx.x * blockDim.x + threadIdx.x; i < total;
       i += gridDim.x * blockDim.x) {
    const size_t g = (size_t)(i / 20) * XDK + 300 + (i % 20);
    xdHi[g] = 0;
    xdLo[g] = 0;
  }
}

// ---------------------------------------------------------------------------
// GEMM 1 (unchanged from R18 — verified 214 us): w = x @ proj_w^T.
// BM=64, BN=320, BK=32, 4 waves; B via global_load_lds, A via VGPR convert.
// (Cannot double-buffer: B dbuf would need 96KB -> 1 blk/CU, m132 mode.)
// ---------------------------------------------------------------------------
__global__ __launch_bounds__(256, 2) void gemm1_xw(
    const float* __restrict__ x, const ushort* __restrict__ pwHi,
    const ushort* __restrict__ pwLo, ushort* __restrict__ wHi,
    ushort* __restrict__ wLo) {
  __shared__ ushort aH[64][32], aL[64][32];
  __shared__ ushort bH[320][32], bL[320][32];
  const int t = threadIdx.x;
  const int lane = t & 63, wv = t >> 6;
  const int l15 = lane & 15, l4 = lane >> 4;
  const int m0 = blockIdx.x * 64;
  const int arow = t >> 2, aslot = t & 3;
  const int lrow4 = lane >> 2, lslot = lane & 3;

  f32x4 acc[4][5];
#pragma unroll
  for (int i = 0; i < 4; ++i)
#pragma unroll
    for (int j = 0; j < 5; ++j) acc[i][j] = (f32x4){0.f, 0.f, 0.f, 0.f};

  for (int k0 = 0; k0 < DIMC; k0 += 32) {
    __syncthreads();
#pragma unroll
    for (int c = 0; c < 5; ++c) {
      const int r0 = wv * 80 + c * 16;
      const size_t g = (size_t)(r0 + lrow4) * DIMC + k0 + lslot * 8;
      gload_lds16(&pwHi[g], &bH[r0][0]);
      gload_lds16(&pwLo[g], &bL[r0][0]);
    }
    {
      float v[8];
      const int m = m0 + arow;
      if (m < MTOT) {
        const float* xp = &x[(size_t)m * DIMC + k0 + aslot * 8];
        const float4 u0 = *(const float4*)xp;
        const float4 u1 = *(const float4*)(xp + 4);
        v[0] = u0.x; v[1] = u0.y; v[2] = u0.z; v[3] = u0.w;
        v[4] = u1.x; v[5] = u1.y; v[6] = u1.z; v[7] = u1.w;
      } else {
#pragma unroll
        for (int j = 0; j < 8; ++j) v[j] = 0.f;
      }
      short8 th, tl;
#pragma unroll
      for (int j = 0; j < 8; ++j) {
        const ushort hh = f2bf(v[j]);
        th[j] = (short)hh;
        tl[j] = (short)f2bf(v[j] - bf2f(hh));
      }
      *(short8*)&aH[arow][aslot * 8] = th;
      *(short8*)&aL[arow][aslot * 8] = tl;
    }
    __syncthreads();

    short8 ah[4], al[4];
#pragma unroll
    for (int i = 0; i < 4; ++i) {
      ah[i] = *(const short8*)&aH[i * 16 + l15][l4 * 8];
      al[i] = *(const short8*)&aL[i * 16 + l15][l4 * 8];
    }
#pragma unroll
    for (int j = 0; j < 5; ++j) {
      const int brow = wv * 80 + j * 16 + l15;
      const short8 bhf = *(const short8*)&bH[brow][l4 * 8];
      const short8 blf = *(const short8*)&bL[brow][l4 * 8];
#pragma unroll
      for (int i = 0; i < 4; ++i) {
        acc[i][j] = __builtin_amdgcn_mfma_f32_16x16x32_bf16(ah[i], bhf, acc[i][j], 0, 0, 0);
        acc[i][j] = __builtin_amdgcn_mfma_f32_16x16x32_bf16(al[i], bhf, acc[i][j], 0, 0, 0);
        acc[i][j] = __builtin_amdgcn_mfma_f32_16x16x32_bf16(ah[i], blf, acc[i][j], 0, 0, 0);
      }
    }
  }

#pragma unroll
  for (int j = 0; j < 5; ++j) {
    const int col = wv * 80 + j * 16 + l15;
    if (col >= INNERC) continue;
#pragma unroll
    for (int i = 0; i < 4; ++i)
#pragma unroll
      for (int r = 0; r < 4; ++r) {
        const int m = m0 + i * 16 + l4 * 4 + r;
        if (m < MTOT) {
          const float val = acc[i][j][r];
          const ushort hh = f2bf(val);
          const size_t g = (size_t)m * INNERC + col;
          wHi[g] = hh;
          wLo[g] = f2bf(val - bf2f(hh));
        }
      }
  }
}

// ---------------------------------------------------------------------------
// GEMM 2 (T3 minimum-2-phase): out = xd(planes) @ out_w(planes)^T + bias.
// Double-buffered LDS (80KB -> 2 blk/CU): STAGE(next) issued BEFORE compute
// of current tile; the single __syncthreads per K-step drains DMAs that were
// in flight during the whole MFMA phase.  WAR-safe: buf overwritten at step t
// was last read at t-1, separated by a barrier.
// ---------------------------------------------------------------------------
__global__ __launch_bounds__(256, 2) void gemm2_out(
    const ushort* __restrict__ xdHi, const ushort* __restrict__ xdLo,
    const ushort* __restrict__ owHi, const ushort* __restrict__ owLo,
    const float* __restrict__ out_b, float* __restrict__ out) {
  __shared__ ushort aH[2][64][32], aL[2][64][32];
  __shared__ ushort bH[2][256][32], bL[2][256][32];
  const int t = threadIdx.x;
  const int lane = t & 63, wv = t >> 6;
  const int l15 = lane & 15, l4 = lane >> 4;
  const int nwg = gridDim.x;
  const int q = nwg >> 3, r = nwg & 7;
  const int xcd = blockIdx.x & 7, idx = blockIdx.x >> 3;
  const int wg = (xcd < r ? xcd * (q + 1) : r * (q + 1) + (xcd - r) * q) + idx;
  const int bn = wg % 3, bm = wg / 3;
  const int m0 = bm * 64, n0 = bn * 256;
  const int lrow4 = lane >> 2, lslot = lane & 3;

  f32x4 acc[4][4];
#pragma unroll
  for (int i = 0; i < 4; ++i)
#pragma unroll
    for (int j = 0; j < 4; ++j) acc[i][j] = (f32x4){0.f, 0.f, 0.f, 0.f};

  // STAGE: issue all 10 DMAs for K-tile k0 into buffer buf
#define G2_STAGE(buf, k0)                                                     \
  {                                                                           \
    const int r0a = wv * 16;                                                  \
    const size_t ga = (size_t)(m0 + r0a + lrow4) * XDK + (k0) + lslot * 8;    \
    gload_lds16(&xdHi[ga], &aH[buf][r0a][0]);                                 \
    gload_lds16(&xdLo[ga], &aL[buf][r0a][0]);                                 \
    _Pragma("unroll")                                                         \
    for (int c = 0; c < 4; ++c) {                                             \
      const int r0b = wv * 64 + c * 16;                                       \
      const size_t gb = (size_t)(n0 + r0b + lrow4) * XDK + (k0) + lslot * 8;  \
      gload_lds16(&owHi[gb], &bH[buf][r0b][0]);                               \
      gload_lds16(&owLo[gb], &bL[buf][r0b][0]);                               \
    }                                                                         \
  }

  // prologue: stage tile 0, drain, sync
  G2_STAGE(0, 0)
  __syncthreads();

  int cur = 0;
  for (int ks = 0; ks < 10; ++ks) {
    // issue next tile's DMAs (they progress during the MFMA phase below)
    if (ks < 9) G2_STAGE(cur ^ 1, (ks + 1) * 32)

    short8 ah[4], al[4];
#pragma unroll
    for (int i = 0; i < 4; ++i) {
      ah[i] = *(const short8*)&aH[cur][i * 16 + l15][l4 * 8];
      al[i] = *(const short8*)&aL[cur][i * 16 + l15][l4 * 8];
    }
#pragma unroll
    for (int j = 0; j < 4; ++j) {
      const int brow = wv * 64 + j * 16 + l15;
      const short8 bhf = *(const short8*)&bH[cur][brow][l4 * 8];
      const short8 blf = *(const short8*)&bL[cur][brow][l4 * 8];
#pragma unroll
      for (int i = 0; i < 4; ++i) {
        acc[i][j] = __builtin_amdgcn_mfma_f32_16x16x32_bf16(ah[i], bhf, acc[i][j], 0, 0, 0);
        acc[i][j] = __builtin_amdgcn_mfma_f32_16x16x32_bf16(al[i], bhf, acc[i][j], 0, 0, 0);
        acc[i][j] = __builtin_amdgcn_mfma_f32_16x16x32_bf16(ah[i], blf, acc[i][j], 0, 0, 0);
      }
    }
    __syncthreads();   // drains next-tile DMAs (overlapped) + syncs waves
    cur ^= 1;
  }
#undef G2_STAGE

#pragma unroll
  for (int j = 0; j < 4; ++j) {
    const int col = n0 + wv * 64 + j * 16 + l15;
    const float bv = out_b[col];
#pragma unroll
    for (int i = 0; i < 4; ++i)
#pragma unroll
      for (int r2 = 0; r2 < 4; ++r2) {
        const int m = m0 + i * 16 + l4 * 4 + r2;
        if (m < MTOT) out[(size_t)m * DIMC + col] = acc[i][j][r2] + bv;
      }
  }
}

// ---------------------------------------------------------------------------
// Adaptive avg-pool -> rep fp32 AND padded rep*SCALE hi/lo planes [bh][128][64]
// ---------------------------------------------------------------------------
__global__ void pool_kernel(const ushort* __restrict__ wHi,
                            const ushort* __restrict__ wLo,
                            float* __restrict__ rep,
                            ushort* __restrict__ repPH, ushort* __restrict__ repPL) {
  int q = blockIdx.x, b = blockIdx.y;
  int i = threadIdx.x;
  if (i < INNERC) {
    int pr = q / 10, pc = q % 10;
    float s = 0.f;
    for (int kr = 0; kr < 10; ++kr)
      for (int kc = 0; kc < 10; ++kc) {
        int tok = (pr * 10 + kr) * 100 + (pc * 10 + kc);
        const size_t g = ((size_t)b * NTOK + tok) * INNERC + i;
        s += bf2f(wHi[g]) + bf2f(wLo[g]);
      }
    s *= 0.01f;
    int h = i / DHEAD, d = i % DHEAD;
    rep[(((size_t)b * HEADS + h) * NQ + q) * DHEAD + d] = s;
    const float sv = s * SCALE;
    const ushort hh = f2bf(sv);
    const size_t pg = (((size_t)b * HEADS + h) * 128 + q) * 64 + d;
    repPH[pg] = hh;
    repPL[pg] = f2bf(sv - bf2f(hh));
  }
  // zero d-pad columns 50..63 for this (b,q) across all heads
  for (int j = threadIdx.x; j < HEADS * 14; j += 320) {
    int h2 = j / 14, d2 = DHEAD + (j % 14);
    const size_t pg = (((size_t)b * HEADS + h2) * 128 + q) * 64 + d2;
    repPH[pg] = 0;
    repPL[pg] = 0;
  }
}

// ---------------------------------------------------------------------------
// Stage-1 attention, MFMA split-flash (unchanged — verified)
// ---------------------------------------------------------------------------
__global__ __launch_bounds__(256, 3) void attn1_mfma(
    const ushort* __restrict__ wHi, const ushort* __restrict__ wLo,
    const float* __restrict__ rep,
    float* __restrict__ m_part, float* __restrict__ l_part,
    float* __restrict__ delta_part) {
  const int bh = blockIdx.x, s = blockIdx.y;
  const int b = bh / HEADS, h = bh % HEADS;
  const int t = threadIdx.x;
  const int lane = t & 63, wv = t >> 6;
  const int l15 = lane & 15, l4 = lane >> 4;

  __shared__ ushort Khi[32][72], Klo[32][72];
  __shared__ ushort VThi[64][40], VTlo[64][40];
  __shared__ ushort Phi[128][40], Plo[128][40];

  short8 qhi[2][2], qlo[2][2];
#pragma unroll
  for (int mi = 0; mi < 2; ++mi) {
#pragma unroll
    for (int ks = 0; ks < 2; ++ks) {
      const int qr = 32 * wv + 16 * mi + l15;
      short8 th, tl;
#pragma unroll
      for (int j = 0; j < 8; ++j) {
        const int k = 32 * ks + 8 * l4 + j;
        float v = (qr < NQ && k < DHEAD)
                      ? rep[((size_t)bh * NQ + qr) * DHEAD + k] * SCALE : 0.f;
        ushort hh = f2bf(v);
        th[j] = (short)hh;
        tl[j] = (short)f2bf(v - bf2f(hh));
      }
      qhi[mi][ks] = th; qlo[mi][ks] = tl;
    }
  }

  f32x4 accO[2][4];
  float m_run[2][4], l_run[2][4];
#pragma unroll
  for (int mi = 0; mi < 2; ++mi) {
#pragma unroll
    for (int r = 0; r < 4; ++r) { m_run[mi][r] = NEGBIG; l_run[mi][r] = 0.f; }
#pragma unroll
    for (int di = 0; di < 4; ++di) accO[mi][di] = (f32x4){0.f, 0.f, 0.f, 0.f};
  }

  const int n0 = s * CHUNK;
  const int n1 = min(NTOK, n0 + CHUNK);

  for (int nt = n0; nt < n1; nt += 32) {
    __syncthreads();
#pragma unroll
    for (int i = 0; i < 4; ++i) {
      const int idx = t + i * 256;
      const int tr = idx >> 5;
      const int d = (idx & 31) * 2;
      const bool inb = (nt + tr < n1) && (d < DHEAD);
      uint hv = 0, lv = 0;
      if (inb) {
        const size_t g = ((size_t)b * NTOK + nt + tr) * INNERC + h * DHEAD + d;
        hv = *(const uint*)&wHi[g];
        lv = *(const uint*)&wLo[g];
      }
      *(uint*)&Khi[tr][d] = hv;
      *(uint*)&Klo[tr][d] = lv;
      const int ps = ((((tr >> 3) + (d >> 3)) & 3) << 3) + (tr & 7);
      VThi[d][ps] = (ushort)(hv & 0xffffu);
      VTlo[d][ps] = (ushort)(lv & 0xffffu);
      VThi[d + 1][ps] = (ushort)(hv >> 16);
      VTlo[d + 1][ps] = (ushort)(lv >> 16);
    }
    __syncthreads();

    f32x4 accS[2][2];
#pragma unroll
    for (int mi = 0; mi < 2; ++mi)
#pragma unroll
      for (int ni = 0; ni < 2; ++ni) accS[mi][ni] = (f32x4){0.f, 0.f, 0.f, 0.f};
#pragma unroll
    for (int ks = 0; ks < 2; ++ks) {
      short8 kh[2], kl[2];
#pragma unroll
      for (int ni = 0; ni < 2; ++ni) {
        kh[ni] = *(const short8*)&Khi[16 * ni + l15][32 * ks + 8 * l4];
        kl[ni] = *(const short8*)&Klo[16 * ni + l15][32 * ks + 8 * l4];
      }
#pragma unroll
      for (int mi = 0; mi < 2; ++mi)
#pragma unroll
        for (int ni = 0; ni < 2; ++ni) {
          accS[mi][ni] = __builtin_amdgcn_mfma_f32_16x16x32_bf16(qhi[mi][ks], kh[ni], accS[mi][ni], 0, 0, 0);
          accS[mi][ni] = __builtin_amdgcn_mfma_f32_16x16x32_bf16(qlo[mi][ks], kh[ni], accS[mi][ni], 0, 0, 0);
          accS[mi][ni] = __builtin_amdgcn_mfma_f32_16x16x32_bf16(qhi[mi][ks], kl[ni], accS[mi][ni], 0, 0, 0);
        }
    }

    bool cval[2];
#pragma unroll
    for (int ni = 0; ni < 2; ++ni) cval[ni] = (nt + 16 * ni + l15) < n1;
#pragma unroll
    for (int mi = 0; mi < 2; ++mi) {
#pragma unroll
      for (int ni = 0; ni < 2; ++ni)
        if (!cval[ni]) {
#pragma unroll
          for (int r = 0; r < 4; ++r) accS[mi][ni][r] = NEGBIG;
        }
#pragma unroll
      for (int r = 0; r < 4; ++r) {
        float mx = fmaxf(accS[mi][0][r], accS[mi][1][r]);
        mx = fmaxf(mx, __shfl_xor(mx, 1));
        mx = fmaxf(mx, __shfl_xor(mx, 2));
        mx = fmaxf(mx, __shfl_xor(mx, 4));
        mx = fmaxf(mx, __shfl_xor(mx, 8));
        const float m_new = fmaxf(m_run[mi][r], mx);
        const float sc = __expf(m_run[mi][r] - m_new);
        m_run[mi][r] = m_new;
        l_run[mi][r] *= sc;
#pragma unroll
        for (int di = 0; di < 4; ++di) accO[mi][di][r] *= sc;
        float ps = 0.f;
#pragma unroll
        for (int ni = 0; ni < 2; ++ni) {
          const float p = __expf(accS[mi][ni][r] - m_new);
          accS[mi][ni][r] = p;
          ps += p;
        }
        ps += __shfl_xor(ps, 1);
        ps += __shfl_xor(ps, 2);
        ps += __shfl_xor(ps, 4);
        ps += __shfl_xor(ps, 8);
        l_run[mi][r] += ps;
      }
#pragma unroll
      for (int ni = 0; ni < 2; ++ni)
#pragma unroll
        for (int r = 0; r < 4; ++r) {
          const int row = 32 * wv + 16 * mi + 4 * l4 + r;
          const int col = 16 * ni + l15;
          const float p = accS[mi][ni][r];
          const ushort ph = f2bf(p);
          Phi[row][col] = ph;
          Plo[row][col] = f2bf(p - bf2f(ph));
        }
    }

#pragma unroll
    for (int mi = 0; mi < 2; ++mi) {
      const short8 pah = *(const short8*)&Phi[32 * wv + 16 * mi + l15][8 * l4];
      const short8 pal = *(const short8*)&Plo[32 * wv + 16 * mi + l15][8 * l4];
#pragma unroll
      for (int di = 0; di < 4; ++di) {
        const int vs = (((l4 + 2 * di + (l15 >> 3)) & 3)) << 3;
        const short8 vbh = *(const short8*)&VThi[16 * di + l15][vs];
        const short8 vbl = *(const short8*)&VTlo[16 * di + l15][vs];
        accO[mi][di] = __builtin_amdgcn_mfma_f32_16x16x32_bf16(pah, vbh, accO[mi][di], 0, 0, 0);
        accO[mi][di] = __builtin_amdgcn_mfma_f32_16x16x32_bf16(pal, vbh, accO[mi][di], 0, 0, 0);
        accO[mi][di] = __builtin_amdgcn_mfma_f32_16x16x32_bf16(pah, vbl, accO[mi][di], 0, 0, 0);
      }
    }
  }

  const size_t base = ((size_t)bh * NSPLIT + s) * NQ;
#pragma unroll
  for (int mi = 0; mi < 2; ++mi)
#pragma unroll
    for (int r = 0; r < 4; ++r) {
      const int q = 32 * wv + 16 * mi + 4 * l4 + r;
      if (q < NQ && l15 == 0) {
        m_part[base + q] = m_run[mi][r];
        l_part[base + q] = l_run[mi][r];
      }
#pragma unroll
      for (int di = 0; di < 4; ++di) {
        const int d = 16 * di + l15;
        if (q < NQ && d < DHEAD)
          delta_part[(base + q) * DHEAD + d] = accO[mi][di][r];
      }
    }
}

// ---------------------------------------------------------------------------
// Combine split partials -> reph2, final m,l per (bh,q)
// ---------------------------------------------------------------------------
__global__ __launch_bounds__(256) void attn1_combine(
    const float* __restrict__ rep, const float* __restrict__ m_part,
    const float* __restrict__ l_part, const float* __restrict__ delta_part,
    const float* __restrict__ step_rep,
    float* __restrict__ reph2, float* __restrict__ m_fin, float* __restrict__ l_fin) {
  int bh = blockIdx.x;
  int h = bh % HEADS;
  int t = threadIdx.x;
  __shared__ float Mf[NQ], Lf[NQ];
  if (t < NQ) {
    int q = t;
    float M = -INFINITY;
#pragma unroll
    for (int s2 = 0; s2 < NSPLIT; ++s2)
      M = fmaxf(M, m_part[((size_t)bh * NSPLIT + s2) * NQ + q]);
    float L = 0.f;
#pragma unroll
    for (int s2 = 0; s2 < NSPLIT; ++s2)
      L += l_part[((size_t)bh * NSPLIT + s2) * NQ + q] *
           __expf(m_part[((size_t)bh * NSPLIT + s2) * NQ + q] - M);
    Mf[q] = M; Lf[q] = L;
    m_fin[(size_t)bh * NQ + q] = M;
    l_fin[(size_t)bh * NQ + q] = L;
  }
  __syncthreads();
  float sr = step_rep[h];
  for (int idx = t; idx < NQ * DHEAD; idx += 256) {
    int q = idx / DHEAD, d = idx % DHEAD;
    float sum = 0.f;
#pragma unroll
    for (int s2 = 0; s2 < NSPLIT; ++s2) {
      size_t pb = ((size_t)bh * NSPLIT + s2) * NQ + q;
      sum += __expf(m_part[pb] - Mf[q]) * delta_part[pb * DHEAD + d];
    }
    float rd = sum / Lf[q];
    reph2[(size_t)bh * NQ * DHEAD + idx] =
        rep[(size_t)bh * NQ * DHEAD + idx] + sr * rd;
  }
}

// ---------------------------------------------------------------------------
// Stage-2 self attention -> xqT planes [bh][64][128] (hi/lo), q-pads zeroed
// ---------------------------------------------------------------------------
__global__ __launch_bounds__(256) void attn2_kernel(
    const float* __restrict__ reph2, const float* __restrict__ step_x,
    ushort* __restrict__ xqTH, ushort* __restrict__ xqTL) {
  int bh = blockIdx.x;
  int h = bh % HEADS;
  int t = threadIdx.x;
  __shared__ float r2[NQ * DHEAD];
  __shared__ float att[NQ * NQ];

  for (int idx = t; idx < NQ * DHEAD; idx += 256)
    r2[idx] = reph2[(size_t)bh * NQ * DHEAD + idx];
  __syncthreads();

  for (int idx = t; idx < NQ * NQ; idx += 256) {
    int qq = idx / NQ, jj = idx % NQ;
    float s = 0.f;
#pragma unroll
    for (int k = 0; k < DHEAD; ++k) s += r2[qq * DHEAD + k] * r2[jj * DHEAD + k];
    att[idx] = s * SCALE;
  }
  __syncthreads();
  if (t < NQ) {
    float M = -INFINITY;
    for (int j = 0; j < NQ; ++j) M = fmaxf(M, att[t * NQ + j]);
    float L = 0.f;
    for (int j = 0; j < NQ; ++j) { float e = __expf(att[t * NQ + j] - M); att[t * NQ + j] = e; L += e; }
    float inv = 1.f / L;
    for (int j = 0; j < NQ; ++j) att[t * NQ + j] *= inv;
  }
  __syncthreads();
  float sx = step_x[h];
  for (int idx = t; idx < NQ * DHEAD; idx += 256) {
    int qd_q = idx / DHEAD, d = idx % DHEAD;
    float v = 0.f;
#pragma unroll
    for (int j = 0; j < NQ; ++j) v += att[qd_q * NQ + j] * r2[j * DHEAD + d];
    v *= sx;
    const size_t pg = ((size_t)bh * 64 + d) * 128 + qd_q;
    const ushort hh = f2bf(v);
    xqTH[pg] = hh;
    xqTL[pg] = f2bf(v - bf2f(hh));
  }
  // zero q-pad columns 100..127 for all 64 d-rows
  for (int idx = t; idx < 64 * 28; idx += 256) {
    int d = idx / 28, qq2 = NQ + (idx % 28);
    const size_t pg = ((size_t)bh * 64 + d) * 128 + qq2;
    xqTH[pg] = 0;
    xqTL[pg] = 0;
  }
}

// ---------------------------------------------------------------------------
// Pass 2 v5 (unchanged — verified): TT=128, register-batched B-frags.
// ---------------------------------------------------------------------------
#define TT5 128
__global__ __launch_bounds__(256, 2) void bcast5_kernel(
    const ushort* __restrict__ wHi, const ushort* __restrict__ wLo,
    const ushort* __restrict__ repPH, const ushort* __restrict__ repPL,
    const ushort* __restrict__ xqTH, const ushort* __restrict__ xqTL,
    const float* __restrict__ m_fin, const float* __restrict__ l_fin,
    ushort* __restrict__ xdHi, ushort* __restrict__ xdLo) {
  const int tile = blockIdx.x, bh = blockIdx.y;
  const int b = bh / HEADS, h = bh % HEADS;
  const int tok0 = tile * TT5;
  const int t = threadIdx.x;
  const int lane = t & 63, wv = t >> 6;
  const int l15 = lane & 15, l4 = lane >> 4;

  __shared__ ushort pH[128][72], pL[128][72];

  short8 awh[2][2], awl[2][2];
#pragma unroll
  for (int st = 0; st < 2; ++st) {
    const int tokA = tok0 + st * 64 + 16 * wv + l15;
#pragma unroll
    for (int ks = 0; ks < 2; ++ks) {
      const int kbase = 32 * ks + 8 * l4;
      uint hv[4] = {0, 0, 0, 0}, lv[4] = {0, 0, 0, 0};
      if (tokA < NTOK && kbase < DHEAD) {
        const size_t g = ((size_t)b * NTOK + tokA) * INNERC + h * DHEAD + kbase;
#pragma unroll
        for (int c = 0; c < 4; ++c) {
          hv[c] = *(const uint*)&wHi[g + 2 * c];
          lv[c] = *(const uint*)&wLo[g + 2 * c];
        }
      }
      short8 th, tl;
#pragma unroll
      for (int j = 0; j < 8; ++j) {
        const bool ok = (kbase + j) < DHEAD;
        const ushort hsel = (j & 1) ? (ushort)(hv[j >> 1] >> 16) : (ushort)(hv[j >> 1] & 0xffffu);
        const ushort lsel = (j & 1) ? (ushort)(lv[j >> 1] >> 16) : (ushort)(lv[j >> 1] & 0xffffu);
        th[j] = ok ? (short)hsel : (short)0;
        tl[j] = ok ? (short)lsel : (short)0;
      }
      awh[st][ks] = th;
      awl[st][ks] = tl;
    }
  }

  f32x4 accO[2][4];
#pragma unroll
  for (int st = 0; st < 2; ++st)
#pragma unroll
    for (int di = 0; di < 4; ++di) accO[st][di] = (f32x4){0.f, 0.f, 0.f, 0.f};

#pragma unroll
  for (int qc = 0; qc < 2; ++qc) {
    const int q0 = qc * 64;

    short8 rbh[4][2], rbl[4][2];
#pragma unroll
    for (int ni = 0; ni < 4; ++ni)
#pragma unroll
      for (int ks = 0; ks < 2; ++ks) {
        const size_t rg = (((size_t)bh * 128) + (q0 + 16 * ni + l15)) * 64 + 32 * ks + 8 * l4;
        rbh[ni][ks] = *(const short8*)&repPH[rg];
        rbl[ni][ks] = *(const short8*)&repPL[rg];
      }
    float mq[4], li[4];
    bool vq[4];
#pragma unroll
    for (int ni = 0; ni < 4; ++ni) {
      const int q = q0 + 16 * ni + l15;
      vq[ni] = (q < NQ);
      mq[ni] = vq[ni] ? m_fin[(size_t)bh * NQ + q] : 0.f;
      li[ni] = vq[ni] ? 1.f / l_fin[(size_t)bh * NQ + q] : 0.f;
    }

#pragma unroll
    for (int st = 0; st < 2; ++st) {
      f32x4 accS[4];
#pragma unroll
      for (int ni = 0; ni < 4; ++ni) accS[ni] = (f32x4){0.f, 0.f, 0.f, 0.f};
#pragma unroll
      for (int ks = 0; ks < 2; ++ks)
#pragma unroll
        for (int ni = 0; ni < 4; ++ni) {
          accS[ni] = __builtin_amdgcn_mfma_f32_16x16x32_bf16(awh[st][ks], rbh[ni][ks], accS[ni], 0, 0, 0);
          accS[ni] = __builtin_amdgcn_mfma_f32_16x16x32_bf16(awl[st][ks], rbh[ni][ks], accS[ni], 0, 0, 0);
          accS[ni] = __builtin_amdgcn_mfma_f32_16x16x32_bf16(awh[st][ks], rbl[ni][ks], accS[ni], 0, 0, 0);
        }
#pragma unroll
      for (int ni = 0; ni < 4; ++ni) {
#pragma unroll
        for (int r = 0; r < 4; ++r) {
          const float p = vq[ni] ? __expf(accS[ni][r] - mq[ni]) * li[ni] : 0.f;
          const int row = st * 64 + 16 * wv + 4 * l4 + r;
          const ushort ph = f2bf(p);
          pH[row][16 * ni + l15] = ph;
          pL[row][16 * ni + l15] = f2bf(p - bf2f(ph));
        }
      }
    }

    short8 xbh[4][2], xbl[4][2];
#pragma unroll
    for (int di = 0; di < 4; ++di)
#pragma unroll
      for (int ks2 = 0; ks2 < 2; ++ks2) {
        const size_t xg = (((size_t)bh * 64) + (16 * di + l15)) * 128 + q0 + 32 * ks2 + 8 * l4;
        xbh[di][ks2] = *(const short8*)&xqTH[xg];
        xbl[di][ks2] = *(const short8*)&xqTL[xg];
      }

#pragma unroll
    for (int st = 0; st < 2; ++st) {
#pragma unroll
      for (int ks2 = 0; ks2 < 2; ++ks2) {
        const short8 pah = *(const short8*)&pH[st * 64 + 16 * wv + l15][32 * ks2 + 8 * l4];
        const short8 pal = *(const short8*)&pL[st * 64 + 16 * wv + l15][32 * ks2 + 8 * l4];
#pragma unroll
        for (int di = 0; di < 4; ++di) {
          accO[st][di] = __builtin_amdgcn_mfma_f32_16x16x32_bf16(pah, xbh[di][ks2], accO[st][di], 0, 0, 0);
          accO[st][di] = __builtin_amdgcn_mfma_f32_16x16x32_bf16(pal, xbh[di][ks2], accO[st][di], 0, 0, 0);
          accO[st][di] = __builtin_amdgcn_mfma_f32_16x16x32_bf16(pah, xbl[di][ks2], accO[st][di], 0, 0, 0);
        }
      }
    }
  }

#pragma unroll
  for (int st = 0; st < 2; ++st)
#pragma unroll
    for (int di = 0; di < 4; ++di) {
      const int d = di * 16 + l15;
      if (d >= DHEAD) continue;
#pragma unroll
      for (int r = 0; r < 4; ++r) {
        const int tok = tok0 + st * 64 + wv * 16 + 4 * l4 + r;
        if (tok < NTOK) {
          const float val = accO[st][di][r];
          const ushort hh = f2bf(val);
          const size_t g = ((size_t)b * NTOK + tok) * XDK + h * DHEAD + d;
          xdHi[g] = hh;
          xdLo[g] = f2bf(val - bf2f(hh));
        }
      }
    }
}

// ---------------------------------------------------------------------------
extern "C" void kernel_launch(void* const* d_in, const int* in_sizes, int n_in,
                              void* d_out, int out_size, void* d_ws, size_t ws_size,
                              hipStream_t stream) {
  const float* x        = (const float*)d_in[0];
  const float* proj_w   = (const float*)d_in[1];
  const float* step_x   = (const float*)d_in[2];
  const float* step_rep = (const float*)d_in[3];
  const float* out_w    = (const float*)d_in[4];
  const float* out_b    = (const float*)d_in[5];
  float* out = (float*)d_out;

  uint8_t* p8 = (uint8_t*)d_ws;
  ushort* wHi    = (ushort*)(p8);                  //  48,720,000 B
  ushort* wLo    = (ushort*)(p8 + 48720000);       //  48,720,000
  float*  rep    = (float*) (p8 + 97440000);       //     960,000
  float*  reph2  = (float*) (p8 + 98400000);       //     960,000
  float*  m_part = (float*) (p8 + 100320000);      //     614,400 (48*32*100)
  float*  l_part = (float*) (p8 + 100934400);      //     614,400
  float*  m_fin  = (float*) (p8 + 101548800);      //      19,200
  float*  l_fin  = (float*) (p8 + 101568000);      //      19,200
  ushort* xdHi   = (ushort*)(p8 + 101587200);      //  51,968,000
  ushort* xdLo   = (ushort*)(p8 + 153555200);      //  51,968,000
  ushort* pwHi   = (ushort*)(p8 + 205523200);      //     491,520
  ushort* pwLo   = (ushort*)(p8 + 206014720);      //     491,520
  ushort* owHi   = (ushort*)(p8 + 206506240);      //     491,520
  ushort* owLo   = (ushort*)(p8 + 206997760);      //     491,520
  ushort* repPH  = (ushort*)(p8 + 207489280);      //     786,432 (48*128*64*2)
  ushort* repPL  = (ushort*)(p8 + 208275712);      //     786,432
  ushort* xqTH   = (ushort*)(p8 + 209062144);      //     786,432 (48*64*128*2)
  ushort* xqTL   = (ushort*)(p8 + 209848576);      //     786,432
  // end 210,635,008 B (~210.6 MB) < proven 213.8 MB.
  float* delta = (float*)xdHi;   // consumed by combine BEFORE pad-zero + bcast5

  // 0. pre-split weights
  split_pad<<<960, 256, 0, stream>>>(proj_w, pwHi, pwLo, INNERC, DIMC, 320, DIMC);
  split_pad<<<960, 256, 0, stream>>>(out_w, owHi, owLo, DIMC, INNERC, DIMC, XDK);
  // 1. w planes = x @ proj_w^T (global_load_lds B staging)
  gemm1_xw<<<1269, 256, 0, stream>>>(x, pwHi, pwLo, wHi, wLo);
  // 2. pooling -> rep fp32 + rep*SCALE planes
  pool_kernel<<<dim3(NQ, BATCH), 320, 0, stream>>>(wHi, wLo, rep, repPH, repPL);
  // 3. stage-1 attention + combine (delta aliases xdHi!)
  attn1_mfma<<<dim3(NBH, NSPLIT), 256, 0, stream>>>(wHi, wLo, rep, m_part, l_part, delta);
  attn1_combine<<<NBH, 256, 0, stream>>>(rep, m_part, l_part, delta, step_rep,
                                         reph2, m_fin, l_fin);
  // 3b. zero xd pad columns AFTER delta is consumed, BEFORE bcast5/gemm2
  zero_xd_pad<<<2048, 256, 0, stream>>>(xdHi, xdLo);
  // 4. stage-2 self-attention -> xqT planes
  attn2_kernel<<<NBH, 256, 0, stream>>>(reph2, step_x, xqTH, xqTL);
  // 5. broadcast back -> xd planes (register-batched MFMA)
  bcast5_kernel<<<dim3(80, NBH), 256, 0, stream>>>(
      wHi, wLo, repPH, repPL, xqTH, xqTL, m_fin, l_fin, xdHi, xdLo);
  // 6. out = xd @ out_w^T + bias (double-buffered prefetch, XCD-swizzled)
  gemm2_out<<<3807, 256, 0, stream>>>(xdHi, xdLo, owHi, owLo, out_b, out);
}

// Round 20
// 745.093 us; speedup vs baseline: 1.0367x; 1.0367x over previous
//
#include <hip/hip_runtime.h>
#include <math.h>

#define BATCH   8
#define NTOK    10150
#define DIMC    768
#define INNERC  300
#define HEADS   6
#define DHEAD   50
#define NQ      100
#define NBH     48          // BATCH*HEADS
#define NSPLIT  32
#define CHUNK   320         // 32*320 = 10240 >= 10150
#define SCALE   0.14142135623730951f   // 50^-0.5
#define MTOT    (BATCH*NTOK)           // 81200
#define XDK     320                    // padded K stride for xd planes
#define NEGBIG  -1.0e30f

typedef __attribute__((ext_vector_type(8))) short short8;
typedef __attribute__((ext_vector_type(4))) float f32x4;

__device__ __forceinline__ ushort f2bf(float x) {
  uint u = __float_as_uint(x);
  uint r = (u + 0x7fffu + ((u >> 16) & 1u)) >> 16;
  return (ushort)r;
}
__device__ __forceinline__ float bf2f(ushort h) {
  return __uint_as_float(((uint)h) << 16);
}
// async global->LDS DMA, 16B per lane; LDS dest = wave-uniform base + lane*16
__device__ __forceinline__ void gload_lds16(const void* g, void* l) {
  __builtin_amdgcn_global_load_lds(
      (const __attribute__((address_space(1))) unsigned int*)g,
      (__attribute__((address_space(3))) unsigned int*)l, 16, 0, 0);
}

// ---------------------------------------------------------------------------
// Pre-split fp32 -> padded hi/lo bf16 planes.  dst is [Rp][Cp]; src [R][C].
// ---------------------------------------------------------------------------
__global__ void split_pad(const float* __restrict__ src, ushort* __restrict__ dHi,
                          ushort* __restrict__ dLo, int R, int C, int Rp, int Cp) {
  const int total = Rp * Cp;
  for (int i = blockIdx.x * blockDim.x + threadIdx.x; i < total;
       i += gridDim.x * blockDim.x) {
    const int r = i / Cp, c = i % Cp;
    const float v = (r < R && c < C) ? src[r * C + c] : 0.f;
    const ushort hh = f2bf(v);
    dHi[i] = hh;
    dLo[i] = f2bf(v - bf2f(hh));
  }
}

// ---------------------------------------------------------------------------
// GEMM 1 (R18-verified, 214 us): w = x @ proj_w^T.
// BM=64, BN=320, BK=32, 4 waves; B via global_load_lds, A via VGPR convert.
// ---------------------------------------------------------------------------
__global__ __launch_bounds__(256, 2) void gemm1_xw(
    const float* __restrict__ x, const ushort* __restrict__ pwHi,
    const ushort* __restrict__ pwLo, ushort* __restrict__ wHi,
    ushort* __restrict__ wLo) {
  __shared__ ushort aH[64][32], aL[64][32];
  __shared__ ushort bH[320][32], bL[320][32];
  const int t = threadIdx.x;
  const int lane = t & 63, wv = t >> 6;
  const int l15 = lane & 15, l4 = lane >> 4;
  const int m0 = blockIdx.x * 64;
  const int arow = t >> 2, aslot = t & 3;
  const int lrow4 = lane >> 2, lslot = lane & 3;

  f32x4 acc[4][5];
#pragma unroll
  for (int i = 0; i < 4; ++i)
#pragma unroll
    for (int j = 0; j < 5; ++j) acc[i][j] = (f32x4){0.f, 0.f, 0.f, 0.f};

  for (int k0 = 0; k0 < DIMC; k0 += 32) {
    __syncthreads();
#pragma unroll
    for (int c = 0; c < 5; ++c) {
      const int r0 = wv * 80 + c * 16;
      const size_t g = (size_t)(r0 + lrow4) * DIMC + k0 + lslot * 8;
      gload_lds16(&pwHi[g], &bH[r0][0]);
      gload_lds16(&pwLo[g], &bL[r0][0]);
    }
    {
      float v[8];
      const int m = m0 + arow;
      if (m < MTOT) {
        const float* xp = &x[(size_t)m * DIMC + k0 + aslot * 8];
        const float4 u0 = *(const float4*)xp;
        const float4 u1 = *(const float4*)(xp + 4);
        v[0] = u0.x; v[1] = u0.y; v[2] = u0.z; v[3] = u0.w;
        v[4] = u1.x; v[5] = u1.y; v[6] = u1.z; v[7] = u1.w;
      } else {
#pragma unroll
        for (int j = 0; j < 8; ++j) v[j] = 0.f;
      }
      short8 th, tl;
#pragma unroll
      for (int j = 0; j < 8; ++j) {
        const ushort hh = f2bf(v[j]);
        th[j] = (short)hh;
        tl[j] = (short)f2bf(v[j] - bf2f(hh));
      }
      *(short8*)&aH[arow][aslot * 8] = th;
      *(short8*)&aL[arow][aslot * 8] = tl;
    }
    __syncthreads();

    short8 ah[4], al[4];
#pragma unroll
    for (int i = 0; i < 4; ++i) {
      ah[i] = *(const short8*)&aH[i * 16 + l15][l4 * 8];
      al[i] = *(const short8*)&aL[i * 16 + l15][l4 * 8];
    }
#pragma unroll
    for (int j = 0; j < 5; ++j) {
      const int brow = wv * 80 + j * 16 + l15;
      const short8 bhf = *(const short8*)&bH[brow][l4 * 8];
      const short8 blf = *(const short8*)&bL[brow][l4 * 8];
#pragma unroll
      for (int i = 0; i < 4; ++i) {
        acc[i][j] = __builtin_amdgcn_mfma_f32_16x16x32_bf16(ah[i], bhf, acc[i][j], 0, 0, 0);
        acc[i][j] = __builtin_amdgcn_mfma_f32_16x16x32_bf16(al[i], bhf, acc[i][j], 0, 0, 0);
        acc[i][j] = __builtin_amdgcn_mfma_f32_16x16x32_bf16(ah[i], blf, acc[i][j], 0, 0, 0);
      }
    }
  }

#pragma unroll
  for (int j = 0; j < 5; ++j) {
    const int col = wv * 80 + j * 16 + l15;
    if (col >= INNERC) continue;
#pragma unroll
    for (int i = 0; i < 4; ++i)
#pragma unroll
      for (int r = 0; r < 4; ++r) {
        const int m = m0 + i * 16 + l4 * 4 + r;
        if (m < MTOT) {
          const float val = acc[i][j][r];
          const ushort hh = f2bf(val);
          const size_t g = (size_t)m * INNERC + col;
          wHi[g] = hh;
          wLo[g] = f2bf(val - bf2f(hh));
        }
      }
  }
}

// ---------------------------------------------------------------------------
// GEMM 2 (R18-verified single-buffer; R19's explicit dbuf REGRESSED because
// __syncthreads drains vmcnt(0) including the just-issued prefetch — m99/m100).
// BM=64, BN=256, BK=32, K=320; A+B via global_load_lds.  XCD swizzle.
// ---------------------------------------------------------------------------
__global__ __launch_bounds__(256, 2) void gemm2_out(
    const ushort* __restrict__ xdHi, const ushort* __restrict__ xdLo,
    const ushort* __restrict__ owHi, const ushort* __restrict__ owLo,
    const float* __restrict__ out_b, float* __restrict__ out) {
  __shared__ ushort aH[64][32], aL[64][32];
  __shared__ ushort bH[256][32], bL[256][32];
  const int t = threadIdx.x;
  const int lane = t & 63, wv = t >> 6;
  const int l15 = lane & 15, l4 = lane >> 4;
  const int nwg = gridDim.x;
  const int q = nwg >> 3, r = nwg & 7;
  const int xcd = blockIdx.x & 7, idx = blockIdx.x >> 3;
  const int wg = (xcd < r ? xcd * (q + 1) : r * (q + 1) + (xcd - r) * q) + idx;
  const int bn = wg % 3, bm = wg / 3;
  const int m0 = bm * 64, n0 = bn * 256;
  const int lrow4 = lane >> 2, lslot = lane & 3;

  f32x4 acc[4][4];
#pragma unroll
  for (int i = 0; i < 4; ++i)
#pragma unroll
    for (int j = 0; j < 4; ++j) acc[i][j] = (f32x4){0.f, 0.f, 0.f, 0.f};

  for (int k0 = 0; k0 < XDK; k0 += 32) {
    __syncthreads();
    {
      const int r0 = wv * 16;
      const size_t g = (size_t)(m0 + r0 + lrow4) * XDK + k0 + lslot * 8;
      gload_lds16(&xdHi[g], &aH[r0][0]);
      gload_lds16(&xdLo[g], &aL[r0][0]);
    }
#pragma unroll
    for (int c = 0; c < 4; ++c) {
      const int r0 = wv * 64 + c * 16;
      const size_t g = (size_t)(n0 + r0 + lrow4) * XDK + k0 + lslot * 8;
      gload_lds16(&owHi[g], &bH[r0][0]);
      gload_lds16(&owLo[g], &bL[r0][0]);
    }
    __syncthreads();

    short8 ah[4], al[4];
#pragma unroll
    for (int i = 0; i < 4; ++i) {
      ah[i] = *(const short8*)&aH[i * 16 + l15][l4 * 8];
      al[i] = *(const short8*)&aL[i * 16 + l15][l4 * 8];
    }
#pragma unroll
    for (int j = 0; j < 4; ++j) {
      const int brow = wv * 64 + j * 16 + l15;
      const short8 bhf = *(const short8*)&bH[brow][l4 * 8];
      const short8 blf = *(const short8*)&bL[brow][l4 * 8];
#pragma unroll
      for (int i = 0; i < 4; ++i) {
        acc[i][j] = __builtin_amdgcn_mfma_f32_16x16x32_bf16(ah[i], bhf, acc[i][j], 0, 0, 0);
        acc[i][j] = __builtin_amdgcn_mfma_f32_16x16x32_bf16(al[i], bhf, acc[i][j], 0, 0, 0);
        acc[i][j] = __builtin_amdgcn_mfma_f32_16x16x32_bf16(ah[i], blf, acc[i][j], 0, 0, 0);
      }
    }
  }

#pragma unroll
  for (int j = 0; j < 4; ++j) {
    const int col = n0 + wv * 64 + j * 16 + l15;
    const float bv = out_b[col];
#pragma unroll
    for (int i = 0; i < 4; ++i)
#pragma unroll
      for (int r2 = 0; r2 < 4; ++r2) {
        const int m = m0 + i * 16 + l4 * 4 + r2;
        if (m < MTOT) out[(size_t)m * DIMC + col] = acc[i][j][r2] + bv;
      }
  }
}

// ---------------------------------------------------------------------------
// Adaptive avg-pool -> rep fp32 AND padded rep*SCALE hi/lo planes [bh][128][64]
// ---------------------------------------------------------------------------
__global__ void pool_kernel(const ushort* __restrict__ wHi,
                            const ushort* __restrict__ wLo,
                            float* __restrict__ rep,
                            ushort* __restrict__ repPH, ushort* __restrict__ repPL) {
  int q = blockIdx.x, b = blockIdx.y;
  int i = threadIdx.x;
  if (i < INNERC) {
    int pr = q / 10, pc = q % 10;
    float s = 0.f;
    for (int kr = 0; kr < 10; ++kr)
      for (int kc = 0; kc < 10; ++kc) {
        int tok = (pr * 10 + kr) * 100 + (pc * 10 + kc);
        const size_t g = ((size_t)b * NTOK + tok) * INNERC + i;
        s += bf2f(wHi[g]) + bf2f(wLo[g]);
      }
    s *= 0.01f;
    int h = i / DHEAD, d = i % DHEAD;
    rep[(((size_t)b * HEADS + h) * NQ + q) * DHEAD + d] = s;
    const float sv = s * SCALE;
    const ushort hh = f2bf(sv);
    const size_t pg = (((size_t)b * HEADS + h) * 128 + q) * 64 + d;
    repPH[pg] = hh;
    repPL[pg] = f2bf(sv - bf2f(hh));
  }
  // zero d-pad columns 50..63 for this (b,q) across all heads
  for (int j = threadIdx.x; j < HEADS * 14; j += 320) {
    int h2 = j / 14, d2 = DHEAD + (j % 14);
    const size_t pg = (((size_t)b * HEADS + h2) * 128 + q) * 64 + d2;
    repPH[pg] = 0;
    repPL[pg] = 0;
  }
}

// ---------------------------------------------------------------------------
// Stage-1 attention, MFMA split-flash (unchanged — verified)
// ---------------------------------------------------------------------------
__global__ __launch_bounds__(256, 3) void attn1_mfma(
    const ushort* __restrict__ wHi, const ushort* __restrict__ wLo,
    const float* __restrict__ rep,
    float* __restrict__ m_part, float* __restrict__ l_part,
    float* __restrict__ delta_part) {
  const int bh = blockIdx.x, s = blockIdx.y;
  const int b = bh / HEADS, h = bh % HEADS;
  const int t = threadIdx.x;
  const int lane = t & 63, wv = t >> 6;
  const int l15 = lane & 15, l4 = lane >> 4;

  __shared__ ushort Khi[32][72], Klo[32][72];
  __shared__ ushort VThi[64][40], VTlo[64][40];
  __shared__ ushort Phi[128][40], Plo[128][40];

  short8 qhi[2][2], qlo[2][2];
#pragma unroll
  for (int mi = 0; mi < 2; ++mi) {
#pragma unroll
    for (int ks = 0; ks < 2; ++ks) {
      const int qr = 32 * wv + 16 * mi + l15;
      short8 th, tl;
#pragma unroll
      for (int j = 0; j < 8; ++j) {
        const int k = 32 * ks + 8 * l4 + j;
        float v = (qr < NQ && k < DHEAD)
                      ? rep[((size_t)bh * NQ + qr) * DHEAD + k] * SCALE : 0.f;
        ushort hh = f2bf(v);
        th[j] = (short)hh;
        tl[j] = (short)f2bf(v - bf2f(hh));
      }
      qhi[mi][ks] = th; qlo[mi][ks] = tl;
    }
  }

  f32x4 accO[2][4];
  float m_run[2][4], l_run[2][4];
#pragma unroll
  for (int mi = 0; mi < 2; ++mi) {
#pragma unroll
    for (int r = 0; r < 4; ++r) { m_run[mi][r] = NEGBIG; l_run[mi][r] = 0.f; }
#pragma unroll
    for (int di = 0; di < 4; ++di) accO[mi][di] = (f32x4){0.f, 0.f, 0.f, 0.f};
  }

  const int n0 = s * CHUNK;
  const int n1 = min(NTOK, n0 + CHUNK);

  for (int nt = n0; nt < n1; nt += 32) {
    __syncthreads();
#pragma unroll
    for (int i = 0; i < 4; ++i) {
      const int idx = t + i * 256;
      const int tr = idx >> 5;
      const int d = (idx & 31) * 2;
      const bool inb = (nt + tr < n1) && (d < DHEAD);
      uint hv = 0, lv = 0;
      if (inb) {
        const size_t g = ((size_t)b * NTOK + nt + tr) * INNERC + h * DHEAD + d;
        hv = *(const uint*)&wHi[g];
        lv = *(const uint*)&wLo[g];
      }
      *(uint*)&Khi[tr][d] = hv;
      *(uint*)&Klo[tr][d] = lv;
      const int ps = ((((tr >> 3) + (d >> 3)) & 3) << 3) + (tr & 7);
      VThi[d][ps] = (ushort)(hv & 0xffffu);
      VTlo[d][ps] = (ushort)(lv & 0xffffu);
      VThi[d + 1][ps] = (ushort)(hv >> 16);
      VTlo[d + 1][ps] = (ushort)(lv >> 16);
    }
    __syncthreads();

    f32x4 accS[2][2];
#pragma unroll
    for (int mi = 0; mi < 2; ++mi)
#pragma unroll
      for (int ni = 0; ni < 2; ++ni) accS[mi][ni] = (f32x4){0.f, 0.f, 0.f, 0.f};
#pragma unroll
    for (int ks = 0; ks < 2; ++ks) {
      short8 kh[2], kl[2];
#pragma unroll
      for (int ni = 0; ni < 2; ++ni) {
        kh[ni] = *(const short8*)&Khi[16 * ni + l15][32 * ks + 8 * l4];
        kl[ni] = *(const short8*)&Klo[16 * ni + l15][32 * ks + 8 * l4];
      }
#pragma unroll
      for (int mi = 0; mi < 2; ++mi)
#pragma unroll
        for (int ni = 0; ni < 2; ++ni) {
          accS[mi][ni] = __builtin_amdgcn_mfma_f32_16x16x32_bf16(qhi[mi][ks], kh[ni], accS[mi][ni], 0, 0, 0);
          accS[mi][ni] = __builtin_amdgcn_mfma_f32_16x16x32_bf16(qlo[mi][ks], kh[ni], accS[mi][ni], 0, 0, 0);
          accS[mi][ni] = __builtin_amdgcn_mfma_f32_16x16x32_bf16(qhi[mi][ks], kl[ni], accS[mi][ni], 0, 0, 0);
        }
    }

    bool cval[2];
#pragma unroll
    for (int ni = 0; ni < 2; ++ni) cval[ni] = (nt + 16 * ni + l15) < n1;
#pragma unroll
    for (int mi = 0; mi < 2; ++mi) {
#pragma unroll
      for (int ni = 0; ni < 2; ++ni)
        if (!cval[ni]) {
#pragma unroll
          for (int r = 0; r < 4; ++r) accS[mi][ni][r] = NEGBIG;
        }
#pragma unroll
      for (int r = 0; r < 4; ++r) {
        float mx = fmaxf(accS[mi][0][r], accS[mi][1][r]);
        mx = fmaxf(mx, __shfl_xor(mx, 1));
        mx = fmaxf(mx, __shfl_xor(mx, 2));
        mx = fmaxf(mx, __shfl_xor(mx, 4));
        mx = fmaxf(mx, __shfl_xor(mx, 8));
        const float m_new = fmaxf(m_run[mi][r], mx);
        const float sc = __expf(m_run[mi][r] - m_new);
        m_run[mi][r] = m_new;
        l_run[mi][r] *= sc;
#pragma unroll
        for (int di = 0; di < 4; ++di) accO[mi][di][r] *= sc;
        float ps = 0.f;
#pragma unroll
        for (int ni = 0; ni < 2; ++ni) {
          const float p = __expf(accS[mi][ni][r] - m_new);
          accS[mi][ni][r] = p;
          ps += p;
        }
        ps += __shfl_xor(ps, 1);
        ps += __shfl_xor(ps, 2);
        ps += __shfl_xor(ps, 4);
        ps += __shfl_xor(ps, 8);
        l_run[mi][r] += ps;
      }
#pragma unroll
      for (int ni = 0; ni < 2; ++ni)
#pragma unroll
        for (int r = 0; r < 4; ++r) {
          const int row = 32 * wv + 16 * mi + 4 * l4 + r;
          const int col = 16 * ni + l15;
          const float p = accS[mi][ni][r];
          const ushort ph = f2bf(p);
          Phi[row][col] = ph;
          Plo[row][col] = f2bf(p - bf2f(ph));
        }
    }

#pragma unroll
    for (int mi = 0; mi < 2; ++mi) {
      const short8 pah = *(const short8*)&Phi[32 * wv + 16 * mi + l15][8 * l4];
      const short8 pal = *(const short8*)&Plo[32 * wv + 16 * mi + l15][8 * l4];
#pragma unroll
      for (int di = 0; di < 4; ++di) {
        const int vs = (((l4 + 2 * di + (l15 >> 3)) & 3)) << 3;
        const short8 vbh = *(const short8*)&VThi[16 * di + l15][vs];
        const short8 vbl = *(const short8*)&VTlo[16 * di + l15][vs];
        accO[mi][di] = __builtin_amdgcn_mfma_f32_16x16x32_bf16(pah, vbh, accO[mi][di], 0, 0, 0);
        accO[mi][di] = __builtin_amdgcn_mfma_f32_16x16x32_bf16(pal, vbh, accO[mi][di], 0, 0, 0);
        accO[mi][di] = __builtin_amdgcn_mfma_f32_16x16x32_bf16(pah, vbl, accO[mi][di], 0, 0, 0);
      }
    }
  }

  const size_t base = ((size_t)bh * NSPLIT + s) * NQ;
#pragma unroll
  for (int mi = 0; mi < 2; ++mi)
#pragma unroll
    for (int r = 0; r < 4; ++r) {
      const int q = 32 * wv + 16 * mi + 4 * l4 + r;
      if (q < NQ && l15 == 0) {
        m_part[base + q] = m_run[mi][r];
        l_part[base + q] = l_run[mi][r];
      }
#pragma unroll
      for (int di = 0; di < 4; ++di) {
        const int d = 16 * di + l15;
        if (q < NQ && d < DHEAD)
          delta_part[(base + q) * DHEAD + d] = accO[mi][di][r];
      }
    }
}

// ---------------------------------------------------------------------------
// Combine split partials -> reph2, final m,l per (bh,q)
// ---------------------------------------------------------------------------
__global__ __launch_bounds__(256) void attn1_combine(
    const float* __restrict__ rep, const float* __restrict__ m_part,
    const float* __restrict__ l_part, const float* __restrict__ delta_part,
    const float* __restrict__ step_rep,
    float* __restrict__ reph2, float* __restrict__ m_fin, float* __restrict__ l_fin) {
  int bh = blockIdx.x;
  int h = bh % HEADS;
  int t = threadIdx.x;
  __shared__ float Mf[NQ], Lf[NQ];
  if (t < NQ) {
    int q = t;
    float M = -INFINITY;
#pragma unroll
    for (int s2 = 0; s2 < NSPLIT; ++s2)
      M = fmaxf(M, m_part[((size_t)bh * NSPLIT + s2) * NQ + q]);
    float L = 0.f;
#pragma unroll
    for (int s2 = 0; s2 < NSPLIT; ++s2)
      L += l_part[((size_t)bh * NSPLIT + s2) * NQ + q] *
           __expf(m_part[((size_t)bh * NSPLIT + s2) * NQ + q] - M);
    Mf[q] = M; Lf[q] = L;
    m_fin[(size_t)bh * NQ + q] = M;
    l_fin[(size_t)bh * NQ + q] = L;
  }
  __syncthreads();
  float sr = step_rep[h];
  for (int idx = t; idx < NQ * DHEAD; idx += 256) {
    int q = idx / DHEAD, d = idx % DHEAD;
    float sum = 0.f;
#pragma unroll
    for (int s2 = 0; s2 < NSPLIT; ++s2) {
      size_t pb = ((size_t)bh * NSPLIT + s2) * NQ + q;
      sum += __expf(m_part[pb] - Mf[q]) * delta_part[pb * DHEAD + d];
    }
    float rd = sum / Lf[q];
    reph2[(size_t)bh * NQ * DHEAD + idx] =
        rep[(size_t)bh * NQ * DHEAD + idx] + sr * rd;
  }
}

// ---------------------------------------------------------------------------
// Stage-2 self attention -> xqT planes [bh][64][128] (hi/lo), q-pads zeroed
// ---------------------------------------------------------------------------
__global__ __launch_bounds__(256) void attn2_kernel(
    const float* __restrict__ reph2, const float* __restrict__ step_x,
    ushort* __restrict__ xqTH, ushort* __restrict__ xqTL) {
  int bh = blockIdx.x;
  int h = bh % HEADS;
  int t = threadIdx.x;
  __shared__ float r2[NQ * DHEAD];
  __shared__ float att[NQ * NQ];

  for (int idx = t; idx < NQ * DHEAD; idx += 256)
    r2[idx] = reph2[(size_t)bh * NQ * DHEAD + idx];
  __syncthreads();

  for (int idx = t; idx < NQ * NQ; idx += 256) {
    int qq = idx / NQ, jj = idx % NQ;
    float s = 0.f;
#pragma unroll
    for (int k = 0; k < DHEAD; ++k) s += r2[qq * DHEAD + k] * r2[jj * DHEAD + k];
    att[idx] = s * SCALE;
  }
  __syncthreads();
  if (t < NQ) {
    float M = -INFINITY;
    for (int j = 0; j < NQ; ++j) M = fmaxf(M, att[t * NQ + j]);
    float L = 0.f;
    for (int j = 0; j < NQ; ++j) { float e = __expf(att[t * NQ + j] - M); att[t * NQ + j] = e; L += e; }
    float inv = 1.f / L;
    for (int j = 0; j < NQ; ++j) att[t * NQ + j] *= inv;
  }
  __syncthreads();
  float sx = step_x[h];
  for (int idx = t; idx < NQ * DHEAD; idx += 256) {
    int qd_q = idx / DHEAD, d = idx % DHEAD;
    float v = 0.f;
#pragma unroll
    for (int j = 0; j < NQ; ++j) v += att[qd_q * NQ + j] * r2[j * DHEAD + d];
    v *= sx;
    const size_t pg = ((size_t)bh * 64 + d) * 128 + qd_q;
    const ushort hh = f2bf(v);
    xqTH[pg] = hh;
    xqTL[pg] = f2bf(v - bf2f(hh));
  }
  // zero q-pad columns 100..127 for all 64 d-rows
  for (int idx = t; idx < 64 * 28; idx += 256) {
    int d = idx / 28, qq2 = NQ + (idx % 28);
    const size_t pg = ((size_t)bh * 64 + d) * 128 + qq2;
    xqTH[pg] = 0;
    xqTL[pg] = 0;
  }
}

// ---------------------------------------------------------------------------
// Pass 2 v5 (verified) + fused xd k-pad zeroing (h==0 blocks zero cols
// 300..319 of their tokens — replaces the zero_xd_pad kernel; runs after
// the delta alias is dead, before gemm2, single writer per element).
// ---------------------------------------------------------------------------
#define TT5 128
__global__ __launch_bounds__(256, 2) void bcast5_kernel(
    const ushort* __restrict__ wHi, const ushort* __restrict__ wLo,
    const ushort* __restrict__ repPH, const ushort* __restrict__ repPL,
    const ushort* __restrict__ xqTH, const ushort* __restrict__ xqTL,
    const float* __restrict__ m_fin, const float* __restrict__ l_fin,
    ushort* __restrict__ xdHi, ushort* __restrict__ xdLo) {
  const int tile = blockIdx.x, bh = blockIdx.y;
  const int b = bh / HEADS, h = bh % HEADS;
  const int tok0 = tile * TT5;
  const int t = threadIdx.x;
  const int lane = t & 63, wv = t >> 6;
  const int l15 = lane & 15, l4 = lane >> 4;

  __shared__ ushort pH[128][72], pL[128][72];

  short8 awh[2][2], awl[2][2];
#pragma unroll
  for (int st = 0; st < 2; ++st) {
    const int tokA = tok0 + st * 64 + 16 * wv + l15;
#pragma unroll
    for (int ks = 0; ks < 2; ++ks) {
      const int kbase = 32 * ks + 8 * l4;
      uint hv[4] = {0, 0, 0, 0}, lv[4] = {0, 0, 0, 0};
      if (tokA < NTOK && kbase < DHEAD) {
        const size_t g = ((size_t)b * NTOK + tokA) * INNERC + h * DHEAD + kbase;
#pragma unroll
        for (int c = 0; c < 4; ++c) {
          hv[c] = *(const uint*)&wHi[g + 2 * c];
          lv[c] = *(const uint*)&wLo[g + 2 * c];
        }
      }
      short8 th, tl;
#pragma unroll
      for (int j = 0; j < 8; ++j) {
        const bool ok = (kbase + j) < DHEAD;
        const ushort hsel = (j & 1) ? (ushort)(hv[j >> 1] >> 16) : (ushort)(hv[j >> 1] & 0xffffu);
        const ushort lsel = (j & 1) ? (ushort)(lv[j >> 1] >> 16) : (ushort)(lv[j >> 1] & 0xffffu);
        th[j] = ok ? (short)hsel : (short)0;
        tl[j] = ok ? (short)lsel : (short)0;
      }
      awh[st][ks] = th;
      awl[st][ks] = tl;
    }
  }

  f32x4 accO[2][4];
#pragma unroll
  for (int st = 0; st < 2; ++st)
#pragma unroll
    for (int di = 0; di < 4; ++di) accO[st][di] = (f32x4){0.f, 0.f, 0.f, 0.f};

#pragma unroll
  for (int qc = 0; qc < 2; ++qc) {
    const int q0 = qc * 64;

    short8 rbh[4][2], rbl[4][2];
#pragma unroll
    for (int ni = 0; ni < 4; ++ni)
#pragma unroll
      for (int ks = 0; ks < 2; ++ks) {
        const size_t rg = (((size_t)bh * 128) + (q0 + 16 * ni + l15)) * 64 + 32 * ks + 8 * l4;
        rbh[ni][ks] = *(const short8*)&repPH[rg];
        rbl[ni][ks] = *(const short8*)&repPL[rg];
      }
    float mq[4], li[4];
    bool vq[4];
#pragma unroll
    for (int ni = 0; ni < 4; ++ni) {
      const int q = q0 + 16 * ni + l15;
      vq[ni] = (q < NQ);
      mq[ni] = vq[ni] ? m_fin[(size_t)bh * NQ + q] : 0.f;
      li[ni] = vq[ni] ? 1.f / l_fin[(size_t)bh * NQ + q] : 0.f;
    }

#pragma unroll
    for (int st = 0; st < 2; ++st) {
      f32x4 accS[4];
#pragma unroll
      for (int ni = 0; ni < 4; ++ni) accS[ni] = (f32x4){0.f, 0.f, 0.f, 0.f};
#pragma unroll
      for (int ks = 0; ks < 2; ++ks)
#pragma unroll
        for (int ni = 0; ni < 4; ++ni) {
          accS[ni] = __builtin_amdgcn_mfma_f32_16x16x32_bf16(awh[st][ks], rbh[ni][ks], accS[ni], 0, 0, 0);
          accS[ni] = __builtin_amdgcn_mfma_f32_16x16x32_bf16(awl[st][ks], rbh[ni][ks], accS[ni], 0, 0, 0);
          accS[ni] = __builtin_amdgcn_mfma_f32_16x16x32_bf16(awh[st][ks], rbl[ni][ks], accS[ni], 0, 0, 0);
        }
#pragma unroll
      for (int ni = 0; ni < 4; ++ni) {
#pragma unroll
        for (int r = 0; r < 4; ++r) {
          const float p = vq[ni] ? __expf(accS[ni][r] - mq[ni]) * li[ni] : 0.f;
          const int row = st * 64 + 16 * wv + 4 * l4 + r;
          const ushort ph = f2bf(p);
          pH[row][16 * ni + l15] = ph;
          pL[row][16 * ni + l15] = f2bf(p - bf2f(ph));
        }
      }
    }

    short8 xbh[4][2], xbl[4][2];
#pragma unroll
    for (int di = 0; di < 4; ++di)
#pragma unroll
      for (int ks2 = 0; ks2 < 2; ++ks2) {
        const size_t xg = (((size_t)bh * 64) + (16 * di + l15)) * 128 + q0 + 32 * ks2 + 8 * l4;
        xbh[di][ks2] = *(const short8*)&xqTH[xg];
        xbl[di][ks2] = *(const short8*)&xqTL[xg];
      }

#pragma unroll
    for (int st = 0; st < 2; ++st) {
#pragma unroll
      for (int ks2 = 0; ks2 < 2; ++ks2) {
        const short8 pah = *(const short8*)&pH[st * 64 + 16 * wv + l15][32 * ks2 + 8 * l4];
        const short8 pal = *(const short8*)&pL[st * 64 + 16 * wv + l15][32 * ks2 + 8 * l4];
#pragma unroll
        for (int di = 0; di < 4; ++di) {
          accO[st][di] = __builtin_amdgcn_mfma_f32_16x16x32_bf16(pah, xbh[di][ks2], accO[st][di], 0, 0, 0);
          accO[st][di] = __builtin_amdgcn_mfma_f32_16x16x32_bf16(pal, xbh[di][ks2], accO[st][di], 0, 0, 0);
          accO[st][di] = __builtin_amdgcn_mfma_f32_16x16x32_bf16(pah, xbl[di][ks2], accO[st][di], 0, 0, 0);
        }
      }
    }
  }

#pragma unroll
  for (int st = 0; st < 2; ++st)
#pragma unroll
    for (int di = 0; di < 4; ++di) {
      const int d = di * 16 + l15;
      if (d >= DHEAD) continue;
#pragma unroll
      for (int r = 0; r < 4; ++r) {
        const int tok = tok0 + st * 64 + wv * 16 + 4 * l4 + r;
        if (tok < NTOK) {
          const float val = accO[st][di][r];
          const ushort hh = f2bf(val);
          const size_t g = ((size_t)b * NTOK + tok) * XDK + h * DHEAD + d;
          xdHi[g] = hh;
          xdLo[g] = f2bf(val - bf2f(hh));
        }
      }
    }

  // fused k-pad zeroing: h==0 blocks own cols 300..319 of their tokens
  if (h == 0) {
    for (int idx = t; idx < TT5 * 20; idx += 256) {
      const int tok = tok0 + idx / 20;
      const int c = 300 + (idx % 20);
      if (tok < NTOK) {
        const size_t g = ((size_t)b * NTOK + tok) * XDK + c;
        xdHi[g] = 0;
        xdLo[g] = 0;
      }
    }
  }
}

// ---------------------------------------------------------------------------
extern "C" void kernel_launch(void* const* d_in, const int* in_sizes, int n_in,
                              void* d_out, int out_size, void* d_ws, size_t ws_size,
                              hipStream_t stream) {
  const float* x        = (const float*)d_in[0];
  const float* proj_w   = (const float*)d_in[1];
  const float* step_x   = (const float*)d_in[2];
  const float* step_rep = (const float*)d_in[3];
  const float* out_w    = (const float*)d_in[4];
  const float* out_b    = (const float*)d_in[5];
  float* out = (float*)d_out;

  uint8_t* p8 = (uint8_t*)d_ws;
  ushort* wHi    = (ushort*)(p8);                  //  48,720,000 B
  ushort* wLo    = (ushort*)(p8 + 48720000);       //  48,720,000
  float*  rep    = (float*) (p8 + 97440000);       //     960,000
  float*  reph2  = (float*) (p8 + 98400000);       //     960,000
  float*  m_part = (float*) (p8 + 100320000);      //     614,400 (48*32*100)
  float*  l_part = (float*) (p8 + 100934400);      //     614,400
  float*  m_fin  = (float*) (p8 + 101548800);      //      19,200
  float*  l_fin  = (float*) (p8 + 101568000);      //      19,200
  ushort* xdHi   = (ushort*)(p8 + 101587200);      //  51,968,000
  ushort* xdLo   = (ushort*)(p8 + 153555200);      //  51,968,000
  ushort* pwHi   = (ushort*)(p8 + 205523200);      //     491,520
  ushort* pwLo   = (ushort*)(p8 + 206014720);      //     491,520
  ushort* owHi   = (ushort*)(p8 + 206506240);      //     491,520
  ushort* owLo   = (ushort*)(p8 + 206997760);      //     491,520
  ushort* repPH  = (ushort*)(p8 + 207489280);      //     786,432 (48*128*64*2)
  ushort* repPL  = (ushort*)(p8 + 208275712);      //     786,432
  ushort* xqTH   = (ushort*)(p8 + 209062144);      //     786,432 (48*64*128*2)
  ushort* xqTL   = (ushort*)(p8 + 209848576);      //     786,432
  // end 210,635,008 B (~210.6 MB) < proven 213.8 MB.
  float* delta = (float*)xdHi;   // consumed by combine BEFORE bcast5

  // 0. pre-split weights
  split_pad<<<960, 256, 0, stream>>>(proj_w, pwHi, pwLo, INNERC, DIMC, 320, DIMC);
  split_pad<<<960, 256, 0, stream>>>(out_w, owHi, owLo, DIMC, INNERC, DIMC, XDK);
  // 1. w planes = x @ proj_w^T (global_load_lds B staging)
  gemm1_xw<<<1269, 256, 0, stream>>>(x, pwHi, pwLo, wHi, wLo);
  // 2. pooling -> rep fp32 + rep*SCALE planes
  pool_kernel<<<dim3(NQ, BATCH), 320, 0, stream>>>(wHi, wLo, rep, repPH, repPL);
  // 3. stage-1 attention + combine (delta aliases xdHi!)
  attn1_mfma<<<dim3(NBH, NSPLIT), 256, 0, stream>>>(wHi, wLo, rep, m_part, l_part, delta);
  attn1_combine<<<NBH, 256, 0, stream>>>(rep, m_part, l_part, delta, step_rep,
                                         reph2, m_fin, l_fin);
  // 4. stage-2 self-attention -> xqT planes
  attn2_kernel<<<NBH, 256, 0, stream>>>(reph2, step_x, xqTH, xqTL);
  // 5. broadcast back -> xd planes (+ fused k-pad zeroing)
  bcast5_kernel<<<dim3(80, NBH), 256, 0, stream>>>(
      wHi, wLo, repPH, repPL, xqTH, xqTL, m_fin, l_fin, xdHi, xdLo);
  // 6. out = xd @ out_w^T + bias (single-buffer gload staging, XCD-swizzled)
  gemm2_out<<<3807, 256, 0, stream>>>(xdHi, xdLo, owHi, owLo, out_b, out);
}